// Round 12
// baseline (81.745 us; speedup 1.0000x reference)
//
#include <hip/hip_runtime.h>
#include <hip/hip_bf16.h>

// BlockAttention: paged KV-cache prefill attention, block-causal mask.
// B=4, LQ=512, HQ=16, HKV=8, D=128, CTX=2048, LK=2560.
// R1: XCD-aware block index. R2: swizzled K/V LDS, dbuf, 1 barrier/tile.
// R3: swapped QK^T, in-register softmax, zero-shuffle PV, defer-max.
// R8/R9: producer/consumer wave split (4C+4P), DS reads halved,
//        conflict-free staging. bench 73.9us.
// R10 (REVERTED): cross-tile pipeline + setprio regressed to 81.6us —
//        merged MFMA cluster killed the natural SM/ds_read overlap.
// R11: R9 schedule, VALU-only cuts: (1) exp2 domain (bare v_exp_f32,
//      log2e folded into Q scale); (2) row-sum l via all-ones MFMA in PV
//      (removes 32 adds + 4 DS-pipe shfls; lrow state gone); (3) fmax3
//      max tree. No schedule/barrier/buffer changes.

#define B_    4
#define LQ_   512
#define HQ_   16
#define HKV_  8
#define D_    128
#define BLKSZ_ 256
#define BPS_  8
#define CTX_  2048
#define DIFFB_ 128
#define KT_   64
#define SCALE2_ 0.1275174457576656f   // (1/sqrt(128)) * log2(e)
#define THR2_   11.541560327111707f   // 8 * log2(e)

typedef __attribute__((ext_vector_type(4))) float f32x4;
typedef __attribute__((ext_vector_type(8))) short bf16x8;
typedef __attribute__((ext_vector_type(2))) unsigned u32x2;

__device__ __forceinline__ unsigned cvt_pk2(float a, float b) {
  union { __hip_bfloat162 h; unsigned u; } x;
  x.h = __float22bfloat162_rn(float2{a, b});
  return x.u;
}
union bf8u { bf16x8 v; unsigned u[4]; };

__device__ __forceinline__ float fmax3f(float a, float b, float c) {
  return fmaxf(fmaxf(a, b), c);   // clang fuses to v_max3_f32
}

// ---- K tile swizzle (units: shorts), 16B-chunk XOR ----
__device__ __forceinline__ int kidx(int kv, int d) {
  return kv * 128 + ((((d >> 3) ^ kv) & 15) << 3) + (d & 7);
}
// ---- V^T tile swizzle; p is the PHYSICAL (k-label) kv slot ----
__device__ __forceinline__ int vidx(int d, int p) {
  return d * 64 + ((((p >> 3) ^ d ^ (d >> 3)) & 7) << 3) + (p & 7);
}
// kv bit-permute: swap bits[5:4] <-> bits[3:2] (involution, keeps [1:0])
__device__ __forceinline__ int pkmap(int kv) {
  return ((kv & 12) << 2) | ((kv & 48) >> 2) | (kv & 3);
}

__global__ __launch_bounds__(512, 2)
void block_attn_kernel(const float* __restrict__ qg,
                       const float* __restrict__ kcur,
                       const float* __restrict__ vcur,
                       const float* __restrict__ kcache,
                       const float* __restrict__ vcache,
                       const int*   __restrict__ btab,
                       float*       __restrict__ out) {
  // grid 256: blk = qb*32 + b*8 + hkv (qb high bits -> same (b,hkv) per XCD)
  const int blk  = blockIdx.x;
  const int hkv  = blk & 7;
  const int b    = (blk >> 3) & 3;
  const int qb   = blk >> 5;                    // 64-row q tile, 0..7
  const int tid  = threadIdx.x;
  const int lane = tid & 63;
  const int wave = tid >> 6;                    // 0..7
  const int lo   = lane & 15;
  const int hi   = lane >> 4;
  const int nt   = (CTX_ + (qb / 2 + 1) * DIFFB_) / KT_;

  __shared__ __align__(16) short Kl[2][KT_ * D_];   // 2 x 16 KiB, swizzled
  __shared__ __align__(16) short Vl[2][D_ * KT_];   // 2 x 16 KiB, V^T perm+swz

  if (wave < 4) {
    // ================= CONSUMER: 32 q-rows x 64 kv ====================
    const int hq    = hkv * 2 + (wave >> 1);
    const int qrow0 = qb * 64 + (wave & 1) * 32;

    // Q fragments (scaled into exp2 domain)
    bf16x8 qf[2][4];
#pragma unroll
    for (int sub = 0; sub < 2; ++sub) {
      const float* qr = qg + ((size_t)((b * LQ_ + qrow0 + sub * 16 + lo)) * HQ_ + hq) * D_;
#pragma unroll
      for (int db = 0; db < 4; ++db) {
        const int d0 = db * 32 + hi * 8;
        f32x4 a  = *(const f32x4*)(qr + d0);
        f32x4 c4 = *(const f32x4*)(qr + d0 + 4);
        bf8u f;
        f.u[0] = cvt_pk2(a[0] * SCALE2_, a[1] * SCALE2_);
        f.u[1] = cvt_pk2(a[2] * SCALE2_, a[3] * SCALE2_);
        f.u[2] = cvt_pk2(c4[0] * SCALE2_, c4[1] * SCALE2_);
        f.u[3] = cvt_pk2(c4[2] * SCALE2_, c4[3] * SCALE2_);
        qf[sub][db] = f.v;
      }
    }

    f32x4 oacc[2][8];
#pragma unroll
    for (int s = 0; s < 2; ++s)
#pragma unroll
      for (int i = 0; i < 8; ++i) oacc[s][i] = (f32x4){0.f, 0.f, 0.f, 0.f};
    f32x4 oaccL[2] = {(f32x4){0.f, 0.f, 0.f, 0.f}, (f32x4){0.f, 0.f, 0.f, 0.f}};
    float mrow[2] = {-1e30f, -1e30f};
    bf16x8 ones;
    {
      bf8u o;
      o.u[0] = o.u[1] = o.u[2] = o.u[3] = 0x3F803F80u;   // bf16 1.0 x8
      ones = o.v;
    }

    __syncthreads();   // prologue staging done

    for (int t = 0; t < nt; ++t) {
      const short* Kb = Kl[t & 1];
      const short* Vb = Vl[t & 1];

      // ---- S^T = K Q^T : each kf feeds BOTH subtiles ----
      f32x4 sacc[2][4];
#pragma unroll
      for (int s = 0; s < 2; ++s)
#pragma unroll
        for (int cs = 0; cs < 4; ++cs) sacc[s][cs] = (f32x4){0.f, 0.f, 0.f, 0.f};
#pragma unroll
      for (int cs = 0; cs < 4; ++cs) {
#pragma unroll
        for (int db = 0; db < 4; ++db) {
          bf16x8 kf = *(const bf16x8*)&Kb[kidx(cs * 16 + lo, db * 32 + hi * 8)];
          sacc[0][cs] = __builtin_amdgcn_mfma_f32_16x16x32_bf16(kf, qf[0][db], sacc[0][cs], 0, 0, 0);
          sacc[1][cs] = __builtin_amdgcn_mfma_f32_16x16x32_bf16(kf, qf[1][db], sacc[1][cs], 0, 0, 0);
        }
      }

      // ---- in-register online softmax (exp2 domain) + pa pack ----
      bf16x8 pa[2][2];
#pragma unroll
      for (int sub = 0; sub < 2; ++sub) {
        float x0 = fmax3f(sacc[sub][0][0], sacc[sub][0][1], sacc[sub][0][2]);
        float x1 = fmax3f(sacc[sub][0][3], sacc[sub][1][0], sacc[sub][1][1]);
        float x2 = fmax3f(sacc[sub][1][2], sacc[sub][1][3], sacc[sub][2][0]);
        float x3 = fmax3f(sacc[sub][2][1], sacc[sub][2][2], sacc[sub][2][3]);
        float x4 = fmax3f(sacc[sub][3][0], sacc[sub][3][1], sacc[sub][3][2]);
        float mx = fmaxf(fmax3f(x0, x1, x2), fmax3f(x3, x4, sacc[sub][3][3]));
        mx = fmaxf(mx, __shfl_xor(mx, 16));
        mx = fmaxf(mx, __shfl_xor(mx, 32));
        const bool keep = __all(mx - mrow[sub] <= THR2_);   // defer-max
        if (!keep) {
          const float mnew = fmaxf(mrow[sub], mx);
          const float sc = exp2f(mrow[sub] - mnew);
          mrow[sub] = mnew;
#pragma unroll
          for (int dt = 0; dt < 8; ++dt) oacc[sub][dt] *= sc;
          oaccL[sub] *= sc;
        }
        const float m = mrow[sub];
#pragma unroll
        for (int cs = 0; cs < 4; ++cs)
#pragma unroll
          for (int i = 0; i < 4; ++i)
            sacc[sub][cs][i] = exp2f(sacc[sub][cs][i] - m);
#pragma unroll
        for (int ch = 0; ch < 2; ++ch) {
          bf8u p;
          p.u[0] = cvt_pk2(sacc[sub][2 * ch][0],     sacc[sub][2 * ch][1]);
          p.u[1] = cvt_pk2(sacc[sub][2 * ch][2],     sacc[sub][2 * ch][3]);
          p.u[2] = cvt_pk2(sacc[sub][2 * ch + 1][0], sacc[sub][2 * ch + 1][1]);
          p.u[3] = cvt_pk2(sacc[sub][2 * ch + 1][2], sacc[sub][2 * ch + 1][3]);
          pa[sub][ch] = p.v;
        }
      }

      // ---- O^T += V^T P^T ; l via all-ones MFMA (free on MFMA pipe) ----
#pragma unroll
      for (int ch = 0; ch < 2; ++ch) {
#pragma unroll
        for (int dt = 0; dt < 8; ++dt) {
          bf16x8 vf = *(const bf16x8*)&Vb[vidx(dt * 16 + lo, hi * 16 + ch * 8)];
          oacc[0][dt] = __builtin_amdgcn_mfma_f32_16x16x32_bf16(vf, pa[0][ch], oacc[0][dt], 0, 0, 0);
          oacc[1][dt] = __builtin_amdgcn_mfma_f32_16x16x32_bf16(vf, pa[1][ch], oacc[1][dt], 0, 0, 0);
        }
        oaccL[0] = __builtin_amdgcn_mfma_f32_16x16x32_bf16(ones, pa[0][ch], oaccL[0], 0, 0, 0);
        oaccL[1] = __builtin_amdgcn_mfma_f32_16x16x32_bf16(ones, pa[1][ch], oaccL[1], 0, 0, 0);
      }

      __syncthreads();   // C: no VMEM in flight; drains lgkm only
    }

    // ---- epilogue: l = oaccL[sub][0] (replicated across i and hi) ----
#pragma unroll
    for (int sub = 0; sub < 2; ++sub) {
      const float inv = 1.f / oaccL[sub][0];
      float* orow = out + ((size_t)(b * LQ_ + qrow0 + sub * 16 + lo) * HQ_ + hq) * D_;
#pragma unroll
      for (int dt = 0; dt < 8; ++dt) {
        f32x4 o4 = oacc[sub][dt] * inv;
        *(f32x4*)(orow + dt * 16 + hi * 4) = o4;
      }
    }
  } else {
    // ================= PRODUCER: stage global -> bf16 -> LDS ==========
    const int pid = tid & 255;           // 0..255
    const int cK  = pid >> 4;            // K row base (+16*i), i=0..3
    const int e   = pid & 15;            // K d-chunk (8 floats at e*8)
    const int qd  = pid >> 4;            // V row-quad 0..15
    const int dc  = pid & 15;            // V d-chunk (8 floats at dc*8)
    const int r0v = qd * 4;
    const int d0v = dc * 8;
    const int P0v = pkmap(r0v);          // rows r0v..r0v+3 -> P0v..P0v+3
    f32x4 kreg[4][2], vreg[4][2];

    auto issue_loads = [&](int t) {
      const int kbase = t * KT_;         // tile never straddles CTX
      const float *kb_, *vb_;
      if (kbase < CTX_) {
        const int pb = btab[b * BPS_ + (kbase >> 8)];
        const size_t base = ((size_t)(pb * BLKSZ_ + (kbase & 255)) * HKV_ + hkv) * D_;
        kb_ = kcache + base; vb_ = vcache + base;
      } else {
        const size_t base = ((size_t)(b * LQ_ + (kbase - CTX_)) * HKV_ + hkv) * D_;
        kb_ = kcur + base;  vb_ = vcur + base;
      }
      const size_t rs = (size_t)HKV_ * D_;
#pragma unroll
      for (int i = 0; i < 4; ++i) {
        const float* kr = kb_ + (size_t)(cK + 16 * i) * rs + e * 8;
        kreg[i][0] = *(const f32x4*)(kr);
        kreg[i][1] = *(const f32x4*)(kr + 4);
      }
#pragma unroll
      for (int m = 0; m < 4; ++m) {
        const float* vr = vb_ + (size_t)(r0v + m) * rs + d0v;
        vreg[m][0] = *(const f32x4*)(vr);
        vreg[m][1] = *(const f32x4*)(vr + 4);
      }
    };

    auto write_lds = [&](int bsel) {
      short* Kb = Kl[bsel];
      short* Vb = Vl[bsel];
#pragma unroll
      for (int i = 0; i < 4; ++i) {      // one b128 per K row-chunk
        bf8u f;
        f.u[0] = cvt_pk2(kreg[i][0][0], kreg[i][0][1]);
        f.u[1] = cvt_pk2(kreg[i][0][2], kreg[i][0][3]);
        f.u[2] = cvt_pk2(kreg[i][1][0], kreg[i][1][1]);
        f.u[3] = cvt_pk2(kreg[i][1][2], kreg[i][1][3]);
        *(bf16x8*)&Kb[kidx(cK + 16 * i, e * 8)] = f.v;
      }
#pragma unroll
      for (int j = 0; j < 8; ++j) {      // one b64 per d: 4 quad-rows packed
        u32x2 w;
        w[0] = cvt_pk2(vreg[0][j >> 2][j & 3], vreg[1][j >> 2][j & 3]);
        w[1] = cvt_pk2(vreg[2][j >> 2][j & 3], vreg[3][j >> 2][j & 3]);
        *(u32x2*)&Vb[vidx(d0v + j, P0v)] = w;
      }
    };

    issue_loads(0);
    write_lds(0);
    if (nt > 1) issue_loads(1);
    asm volatile("s_waitcnt lgkmcnt(0)" ::: "memory");
    __builtin_amdgcn_s_barrier();

    for (int t = 0; t < nt; ++t) {
      if (t + 1 < nt) write_lds((t + 1) & 1);   // auto vmcnt wait on reg use
      if (t + 2 < nt) issue_loads(t + 2);       // in flight across barrier
      asm volatile("s_waitcnt lgkmcnt(0)" ::: "memory");
      __builtin_amdgcn_s_barrier();
    }
  }
}

extern "C" void kernel_launch(void* const* d_in, const int* in_sizes, int n_in,
                              void* d_out, int out_size, void* d_ws, size_t ws_size,
                              hipStream_t stream) {
  (void)in_sizes; (void)n_in; (void)out_size; (void)d_ws; (void)ws_size;
  const float* q      = (const float*)d_in[0];
  const float* k      = (const float*)d_in[1];
  const float* v      = (const float*)d_in[2];
  const float* kcache = (const float*)d_in[3];
  const float* vcache = (const float*)d_in[4];
  const int*   btab   = (const int*)d_in[5];
  float* out = (float*)d_out;

  block_attn_kernel<<<dim3(B_ * HKV_ * (LQ_ / 64)), dim3(512), 0, stream>>>(
      q, k, v, kcache, vcache, btab, out);
}

// Round 13
// 81.181 us; speedup vs baseline: 1.0069x; 1.0069x over previous
//
#include <hip/hip_runtime.h>
#include <hip/hip_bf16.h>

// BlockAttention: paged KV-cache prefill attention, block-causal mask.
// B=4, LQ=512, HQ=16, HKV=8, D=128, CTX=2048, LK=2560.
// R1: XCD-aware block index. R2: swizzled K/V LDS, dbuf, 1 barrier/tile.
// R3: swapped QK^T, in-register softmax, zero-shuffle PV, defer-max.
// R9: producer/consumer wave split (4C+4P). bench 73.9 / rocprof 108.
// R10/R11: schedule + VALU variants — bench regressed, rocprof flat/better;
//          cross-session bench at the 10% level is untrustworthy (noise).
// R12: 768 threads = 8 C-waves (32q x 32kv each: R6's verified kv-split
//      algebra; per-CU DS reads and MFMA counts IDENTICAL to R9) + 4
//      P-waves (R9 staging verbatim; V slot = per-half pk32). 3 waves/SIMD
//      (2C+1P) so a second C-wave hides each consumer's QK->SM->PV chain.
//      kvh pairs merge once at end via 64KB LDS overlay. VALU code = R9
//      exact (expf, shfl-lrow) for cross-round interpretability.

#define B_    4
#define LQ_   512
#define HQ_   16
#define HKV_  8
#define D_    128
#define BLKSZ_ 256
#define BPS_  8
#define CTX_  2048
#define DIFFB_ 128
#define KT_   64
#define SCALE_ 0.08838834764831845f

typedef __attribute__((ext_vector_type(4))) float f32x4;
typedef __attribute__((ext_vector_type(8))) short bf16x8;
typedef __attribute__((ext_vector_type(2))) unsigned u32x2;

__device__ __forceinline__ unsigned cvt_pk2(float a, float b) {
  union { __hip_bfloat162 h; unsigned u; } x;
  x.h = __float22bfloat162_rn(float2{a, b});
  return x.u;
}
union bf8u { bf16x8 v; unsigned u[4]; };

// ---- K tile swizzle (units: shorts), 16B-chunk XOR ----
__device__ __forceinline__ int kidx(int kv, int d) {
  return kv * 128 + ((((d >> 3) ^ kv) & 15) << 3) + (d & 7);
}
// ---- V^T tile swizzle; p is the PHYSICAL (k-label) kv slot ----
__device__ __forceinline__ int vidx(int d, int p) {
  return d * 64 + ((((p >> 3) ^ d ^ (d >> 3)) & 7) << 3) + (p & 7);
}
// kv -> phys k-label within a 32-half: [4][3:2][1:0] -> [3:2][4][1:0]
__device__ __forceinline__ int pk32(int w) {
  return (((w >> 2) & 3) << 3) | (((w >> 4) & 1) << 2) | (w & 3);
}

__global__ __launch_bounds__(768)
void block_attn_kernel(const float* __restrict__ qg,
                       const float* __restrict__ kcur,
                       const float* __restrict__ vcur,
                       const float* __restrict__ kcache,
                       const float* __restrict__ vcache,
                       const int*   __restrict__ btab,
                       float*       __restrict__ out) {
  // grid 256: blk = qb*32 + b*8 + hkv (qb high bits -> same (b,hkv) per XCD)
  const int blk  = blockIdx.x;
  const int hkv  = blk & 7;
  const int b    = (blk >> 3) & 3;
  const int qb   = blk >> 5;                    // 64-row q tile, 0..7
  const int tid  = threadIdx.x;
  const int lane = tid & 63;
  const int wave = tid >> 6;                    // 0..11
  const int lo   = lane & 15;
  const int hi   = lane >> 4;
  const int nt   = (CTX_ + (qb / 2 + 1) * DIFFB_) / KT_;

  // Kl[2] @0,16384; Vl[2] @32768,49152 (bytes). Merge scratch Os
  // (128 rows x 128 f32 = 64KB) overlays everything after the loop.
  __shared__ __align__(16) char smem[65536];
  __shared__ float ms[8][16], ls[8][16];
  float* Os = (float*)smem;

  if (wave < 8) {
    // ============ CONSUMER: 32 q-rows x 32-kv half, no global loads =====
    const int kvh  = wave & 1;                  // kv half
    const int g    = wave >> 1;                 // 0..3: (head, q-half)
    const int hq    = hkv * 2 + (g >> 1);
    const int qrow0 = qb * 64 + (g & 1) * 32;

    // Q fragments for both 16-row subtiles (scaled bf16)
    bf16x8 qf[2][4];
#pragma unroll
    for (int sub = 0; sub < 2; ++sub) {
      const float* qr = qg + ((size_t)((b * LQ_ + qrow0 + sub * 16 + lo)) * HQ_ + hq) * D_;
#pragma unroll
      for (int db = 0; db < 4; ++db) {
        const int d0 = db * 32 + hi * 8;
        f32x4 a  = *(const f32x4*)(qr + d0);
        f32x4 c4 = *(const f32x4*)(qr + d0 + 4);
        bf8u f;
        f.u[0] = cvt_pk2(a[0] * SCALE_, a[1] * SCALE_);
        f.u[1] = cvt_pk2(a[2] * SCALE_, a[3] * SCALE_);
        f.u[2] = cvt_pk2(c4[0] * SCALE_, c4[1] * SCALE_);
        f.u[3] = cvt_pk2(c4[2] * SCALE_, c4[3] * SCALE_);
        qf[sub][db] = f.v;
      }
    }

    f32x4 oacc[2][8];
#pragma unroll
    for (int s = 0; s < 2; ++s)
#pragma unroll
      for (int i = 0; i < 8; ++i) oacc[s][i] = (f32x4){0.f, 0.f, 0.f, 0.f};
    float mrow[2] = {-1e30f, -1e30f}, lrow[2] = {0.f, 0.f};

    __syncthreads();   // prologue staging done

    for (int t = 0; t < nt; ++t) {
      const short* Kb = (const short*)(smem + (t & 1) * 16384);
      const short* Vb = (const short*)(smem + 32768 + (t & 1) * 16384);

      // ---- S^T = K Q^T on this wave's 32-kv half: 8 reads, 16 MFMAs ----
      f32x4 sacc[2][2];
#pragma unroll
      for (int s = 0; s < 2; ++s)
#pragma unroll
        for (int cs = 0; cs < 2; ++cs) sacc[s][cs] = (f32x4){0.f, 0.f, 0.f, 0.f};
#pragma unroll
      for (int cs = 0; cs < 2; ++cs) {
#pragma unroll
        for (int db = 0; db < 4; ++db) {
          bf16x8 kf = *(const bf16x8*)&Kb[kidx(kvh * 32 + cs * 16 + lo,
                                               db * 32 + hi * 8)];
          sacc[0][cs] = __builtin_amdgcn_mfma_f32_16x16x32_bf16(kf, qf[0][db], sacc[0][cs], 0, 0, 0);
          sacc[1][cs] = __builtin_amdgcn_mfma_f32_16x16x32_bf16(kf, qf[1][db], sacc[1][cs], 0, 0, 0);
        }
      }

      // ---- in-register online softmax + pa pack, per subtile ----
      bf16x8 pa[2];
#pragma unroll
      for (int sub = 0; sub < 2; ++sub) {
        float m0 = fmaxf(fmaxf(sacc[sub][0][0], sacc[sub][0][1]),
                         fmaxf(sacc[sub][0][2], sacc[sub][0][3]));
        float m1 = fmaxf(fmaxf(sacc[sub][1][0], sacc[sub][1][1]),
                         fmaxf(sacc[sub][1][2], sacc[sub][1][3]));
        float mx = fmaxf(m0, m1);
        mx = fmaxf(mx, __shfl_xor(mx, 16));
        mx = fmaxf(mx, __shfl_xor(mx, 32));
        const bool keep = __all(mx - mrow[sub] <= 8.0f);   // defer-max
        const float mnew = keep ? mrow[sub] : fmaxf(mrow[sub], mx);
        float rs = 0.f;
#pragma unroll
        for (int cs = 0; cs < 2; ++cs)
#pragma unroll
          for (int i = 0; i < 4; ++i) {
            const float p = __expf(sacc[sub][cs][i] - mnew);
            sacc[sub][cs][i] = p;
            rs += p;
          }
        rs += __shfl_xor(rs, 16);
        rs += __shfl_xor(rs, 32);
        if (keep) {
          lrow[sub] += rs;
        } else {
          const float sc = __expf(mrow[sub] - mnew);
          lrow[sub] = lrow[sub] * sc + rs;
          mrow[sub] = mnew;
#pragma unroll
          for (int dt = 0; dt < 8; ++dt) oacc[sub][dt] *= sc;
        }
        bf8u p;
        p.u[0] = cvt_pk2(sacc[sub][0][0], sacc[sub][0][1]);
        p.u[1] = cvt_pk2(sacc[sub][0][2], sacc[sub][0][3]);
        p.u[2] = cvt_pk2(sacc[sub][1][0], sacc[sub][1][1]);
        p.u[3] = cvt_pk2(sacc[sub][1][2], sacc[sub][1][3]);
        pa[sub] = p.v;
      }

      // ---- O^T += V^T P^T : 8 reads, 16 MFMAs (vf feeds both subs) ----
#pragma unroll
      for (int dt = 0; dt < 8; ++dt) {
        bf16x8 vf = *(const bf16x8*)&Vb[vidx(dt * 16 + lo, kvh * 32 + hi * 8)];
        oacc[0][dt] = __builtin_amdgcn_mfma_f32_16x16x32_bf16(vf, pa[0], oacc[0][dt], 0, 0, 0);
        oacc[1][dt] = __builtin_amdgcn_mfma_f32_16x16x32_bf16(vf, pa[1], oacc[1][dt], 0, 0, 0);
      }

      __syncthreads();   // C: no VMEM in flight; drains lgkm only
    }

    // ---- merge kv-halves: kvh=1 publishes, kvh=0 combines + stores ----
    if (kvh == 1) {
#pragma unroll
      for (int sub = 0; sub < 2; ++sub) {
#pragma unroll
        for (int dt = 0; dt < 8; ++dt)
          *(f32x4*)&Os[(size_t)(g * 32 + sub * 16 + lo) * 128 + dt * 16 + hi * 4] =
              oacc[sub][dt];
        if (hi == 0) { ms[g * 2 + sub][lo] = mrow[sub]; ls[g * 2 + sub][lo] = lrow[sub]; }
      }
    }
    __syncthreads();
    if (kvh == 0) {
#pragma unroll
      for (int sub = 0; sub < 2; ++sub) {
        const float m1 = ms[g * 2 + sub][lo], l1 = ls[g * 2 + sub][lo];
        const float mstar = fmaxf(mrow[sub], m1);
        const float a0 = __expf(mrow[sub] - mstar);
        const float a1 = __expf(m1 - mstar);
        const float linv = 1.f / (lrow[sub] * a0 + l1 * a1);
        float* orow = out + ((size_t)(b * LQ_ + qrow0 + sub * 16 + lo) * HQ_ + hq) * D_;
#pragma unroll
        for (int dt = 0; dt < 8; ++dt) {
          f32x4 o1 = *(const f32x4*)&Os[(size_t)(g * 32 + sub * 16 + lo) * 128 + dt * 16 + hi * 4];
          f32x4 o = (oacc[sub][dt] * a0 + o1 * a1) * linv;
          *(f32x4*)(orow + dt * 16 + hi * 4) = o;
        }
      }
    }
  } else {
    // ================= PRODUCER: stage global -> bf16 -> LDS ==========
    // R9 mapping verbatim; V phys slot = per-half pk32 (consumer reads
    // phys half [kvh*32, kvh*32+32) with R6's verified k-label algebra).
    const int pid = tid & 255;           // 0..255
    const int cK  = pid >> 4;            // K row base (+16*i), i=0..3
    const int e   = pid & 15;            // K d-chunk (8 floats at e*8)
    const int qd  = pid >> 4;            // V row-quad 0..15
    const int dc  = pid & 15;            // V d-chunk (8 floats at dc*8)
    const int r0v = qd * 4;
    const int d0v = dc * 8;
    const int P0v = (r0v & 32) + pk32(r0v & 31);  // 4 consecutive phys slots
    f32x4 kreg[4][2], vreg[4][2];

    auto issue_loads = [&](int t) {
      const int kbase = t * KT_;         // tile never straddles CTX
      const float *kb_, *vb_;
      if (kbase < CTX_) {
        const int pb = btab[b * BPS_ + (kbase >> 8)];
        const size_t base = ((size_t)(pb * BLKSZ_ + (kbase & 255)) * HKV_ + hkv) * D_;
        kb_ = kcache + base; vb_ = vcache + base;
      } else {
        const size_t base = ((size_t)(b * LQ_ + (kbase - CTX_)) * HKV_ + hkv) * D_;
        kb_ = kcur + base;  vb_ = vcur + base;
      }
      const size_t rs = (size_t)HKV_ * D_;
#pragma unroll
      for (int i = 0; i < 4; ++i) {
        const float* kr = kb_ + (size_t)(cK + 16 * i) * rs + e * 8;
        kreg[i][0] = *(const f32x4*)(kr);
        kreg[i][1] = *(const f32x4*)(kr + 4);
      }
#pragma unroll
      for (int m = 0; m < 4; ++m) {
        const float* vr = vb_ + (size_t)(r0v + m) * rs + d0v;
        vreg[m][0] = *(const f32x4*)(vr);
        vreg[m][1] = *(const f32x4*)(vr + 4);
      }
    };

    auto write_lds = [&](int bsel) {
      short* Kb = (short*)(smem + bsel * 16384);
      short* Vb = (short*)(smem + 32768 + bsel * 16384);
#pragma unroll
      for (int i = 0; i < 4; ++i) {      // one b128 per K row-chunk
        bf8u f;
        f.u[0] = cvt_pk2(kreg[i][0][0], kreg[i][0][1]);
        f.u[1] = cvt_pk2(kreg[i][0][2], kreg[i][0][3]);
        f.u[2] = cvt_pk2(kreg[i][1][0], kreg[i][1][1]);
        f.u[3] = cvt_pk2(kreg[i][1][2], kreg[i][1][3]);
        *(bf16x8*)&Kb[kidx(cK + 16 * i, e * 8)] = f.v;
      }
#pragma unroll
      for (int j = 0; j < 8; ++j) {      // one b64 per d: 4 quad-rows packed
        u32x2 w;
        w[0] = cvt_pk2(vreg[0][j >> 2][j & 3], vreg[1][j >> 2][j & 3]);
        w[1] = cvt_pk2(vreg[2][j >> 2][j & 3], vreg[3][j >> 2][j & 3]);
        *(u32x2*)&Vb[vidx(d0v + j, P0v)] = w;
      }
    };

    issue_loads(0);
    write_lds(0);
    if (nt > 1) issue_loads(1);
    asm volatile("s_waitcnt lgkmcnt(0)" ::: "memory");
    __builtin_amdgcn_s_barrier();

    for (int t = 0; t < nt; ++t) {
      if (t + 1 < nt) write_lds((t + 1) & 1);   // auto vmcnt wait on reg use
      if (t + 2 < nt) issue_loads(t + 2);       // in flight across barrier
      asm volatile("s_waitcnt lgkmcnt(0)" ::: "memory");
      __builtin_amdgcn_s_barrier();
    }
    __builtin_amdgcn_s_barrier();   // matches consumers' merge-publish sync
  }
}

extern "C" void kernel_launch(void* const* d_in, const int* in_sizes, int n_in,
                              void* d_out, int out_size, void* d_ws, size_t ws_size,
                              hipStream_t stream) {
  (void)in_sizes; (void)n_in; (void)out_size; (void)d_ws; (void)ws_size;
  const float* q      = (const float*)d_in[0];
  const float* k      = (const float*)d_in[1];
  const float* v      = (const float*)d_in[2];
  const float* kcache = (const float*)d_in[3];
  const float* vcache = (const float*)d_in[4];
  const int*   btab   = (const int*)d_in[5];
  float* out = (float*)d_out;

  block_attn_kernel<<<dim3(B_ * HKV_ * (LQ_ / 64)), dim3(768), 0, stream>>>(
      q, k, v, kcache, vcache, btab, out);
}

// Round 14
// 71.316 us; speedup vs baseline: 1.1462x; 1.1383x over previous
//
#include <hip/hip_runtime.h>
#include <hip/hip_bf16.h>

// BlockAttention: paged KV-cache prefill attention, block-causal mask.
// B=4, LQ=512, HQ=16, HKV=8, D=128, CTX=2048, LK=2560.
// R1: XCD-aware block index. R2: swizzled K/V LDS, dbuf, 1 barrier/tile.
// R3: swapped QK^T, in-register softmax, zero-shuffle PV, defer-max.
// R9: producer/consumer wave split (4C+4P). best bench 73.9 / rocprof 108.
// R10-R12 (all ~neutral): schedule/VALU/occupancy variants — occupancy is
//      NOT the constraint; per-tile lockstep phase bursts are.
// R13: intra-tile phase overlap, R9-exact otherwise: issue all 16 vf
//      ds_read_b128 into a register cache BEFORE SM(sub1); softmax VALU
//      hides the vf latency; PV becomes a dense pure-register 32-MFMA
//      cluster. No index/barrier/producer changes.

#define B_    4
#define LQ_   512
#define HQ_   16
#define HKV_  8
#define D_    128
#define BLKSZ_ 256
#define BPS_  8
#define CTX_  2048
#define DIFFB_ 128
#define KT_   64
#define SCALE_ 0.08838834764831845f

typedef __attribute__((ext_vector_type(4))) float f32x4;
typedef __attribute__((ext_vector_type(8))) short bf16x8;
typedef __attribute__((ext_vector_type(2))) unsigned u32x2;

__device__ __forceinline__ unsigned cvt_pk2(float a, float b) {
  union { __hip_bfloat162 h; unsigned u; } x;
  x.h = __float22bfloat162_rn(float2{a, b});
  return x.u;
}
union bf8u { bf16x8 v; unsigned u[4]; };

// ---- K tile swizzle (units: shorts), 16B-chunk XOR ----
__device__ __forceinline__ int kidx(int kv, int d) {
  return kv * 128 + ((((d >> 3) ^ kv) & 15) << 3) + (d & 7);
}
// ---- V^T tile swizzle; p is the PHYSICAL (k-label) kv slot ----
__device__ __forceinline__ int vidx(int d, int p) {
  return d * 64 + ((((p >> 3) ^ d ^ (d >> 3)) & 7) << 3) + (p & 7);
}
// kv bit-permute: swap bits[5:4] <-> bits[3:2] (involution, keeps [1:0])
__device__ __forceinline__ int pkmap(int kv) {
  return ((kv & 12) << 2) | ((kv & 48) >> 2) | (kv & 3);
}

__global__ __launch_bounds__(512, 2)
void block_attn_kernel(const float* __restrict__ qg,
                       const float* __restrict__ kcur,
                       const float* __restrict__ vcur,
                       const float* __restrict__ kcache,
                       const float* __restrict__ vcache,
                       const int*   __restrict__ btab,
                       float*       __restrict__ out) {
  // grid 256: blk = qb*32 + b*8 + hkv (qb high bits -> same (b,hkv) per XCD)
  const int blk  = blockIdx.x;
  const int hkv  = blk & 7;
  const int b    = (blk >> 3) & 3;
  const int qb   = blk >> 5;                    // 64-row q tile, 0..7
  const int tid  = threadIdx.x;
  const int lane = tid & 63;
  const int wave = tid >> 6;                    // 0..7
  const int lo   = lane & 15;
  const int hi   = lane >> 4;
  const int nt   = (CTX_ + (qb / 2 + 1) * DIFFB_) / KT_;

  __shared__ __align__(16) short Kl[2][KT_ * D_];   // 2 x 16 KiB, swizzled
  __shared__ __align__(16) short Vl[2][D_ * KT_];   // 2 x 16 KiB, V^T perm+swz

  if (wave < 4) {
    // ================= CONSUMER: 32 q-rows x 64 kv ====================
    const int hq    = hkv * 2 + (wave >> 1);
    const int qrow0 = qb * 64 + (wave & 1) * 32;

    // Q fragments for both 16-row subtiles (scaled bf16)
    bf16x8 qf[2][4];
#pragma unroll
    for (int sub = 0; sub < 2; ++sub) {
      const float* qr = qg + ((size_t)((b * LQ_ + qrow0 + sub * 16 + lo)) * HQ_ + hq) * D_;
#pragma unroll
      for (int db = 0; db < 4; ++db) {
        const int d0 = db * 32 + hi * 8;
        f32x4 a  = *(const f32x4*)(qr + d0);
        f32x4 c4 = *(const f32x4*)(qr + d0 + 4);
        bf8u f;
        f.u[0] = cvt_pk2(a[0] * SCALE_, a[1] * SCALE_);
        f.u[1] = cvt_pk2(a[2] * SCALE_, a[3] * SCALE_);
        f.u[2] = cvt_pk2(c4[0] * SCALE_, c4[1] * SCALE_);
        f.u[3] = cvt_pk2(c4[2] * SCALE_, c4[3] * SCALE_);
        qf[sub][db] = f.v;
      }
    }

    f32x4 oacc[2][8];
#pragma unroll
    for (int s = 0; s < 2; ++s)
#pragma unroll
      for (int i = 0; i < 8; ++i) oacc[s][i] = (f32x4){0.f, 0.f, 0.f, 0.f};
    float mrow[2] = {-1e30f, -1e30f}, lrow[2] = {0.f, 0.f};

    __syncthreads();   // prologue staging done

    for (int t = 0; t < nt; ++t) {
      const short* Kb = Kl[t & 1];
      const short* Vb = Vl[t & 1];

      // ---- S^T = K Q^T : each kf feeds BOTH subtiles ----
      f32x4 sacc[2][4];
#pragma unroll
      for (int s = 0; s < 2; ++s)
#pragma unroll
        for (int cs = 0; cs < 4; ++cs) sacc[s][cs] = (f32x4){0.f, 0.f, 0.f, 0.f};
#pragma unroll
      for (int cs = 0; cs < 4; ++cs) {
#pragma unroll
        for (int db = 0; db < 4; ++db) {
          bf16x8 kf = *(const bf16x8*)&Kb[kidx(cs * 16 + lo, db * 32 + hi * 8)];
          sacc[0][cs] = __builtin_amdgcn_mfma_f32_16x16x32_bf16(kf, qf[0][db], sacc[0][cs], 0, 0, 0);
          sacc[1][cs] = __builtin_amdgcn_mfma_f32_16x16x32_bf16(kf, qf[1][db], sacc[1][cs], 0, 0, 0);
        }
      }

      // ---- online softmax, one sub at a time (R9 VALU code) ----
      bf16x8 pa[2][2];
      auto SM = [&](int sub) {
        float m0 = fmaxf(fmaxf(sacc[sub][0][0], sacc[sub][0][1]),
                         fmaxf(sacc[sub][0][2], sacc[sub][0][3]));
        float m1 = fmaxf(fmaxf(sacc[sub][1][0], sacc[sub][1][1]),
                         fmaxf(sacc[sub][1][2], sacc[sub][1][3]));
        float m2 = fmaxf(fmaxf(sacc[sub][2][0], sacc[sub][2][1]),
                         fmaxf(sacc[sub][2][2], sacc[sub][2][3]));
        float m3 = fmaxf(fmaxf(sacc[sub][3][0], sacc[sub][3][1]),
                         fmaxf(sacc[sub][3][2], sacc[sub][3][3]));
        float mx = fmaxf(fmaxf(m0, m1), fmaxf(m2, m3));
        mx = fmaxf(mx, __shfl_xor(mx, 16));
        mx = fmaxf(mx, __shfl_xor(mx, 32));
        const bool keep = __all(mx - mrow[sub] <= 8.0f);   // defer-max
        const float mnew = keep ? mrow[sub] : fmaxf(mrow[sub], mx);
        float rs = 0.f;
#pragma unroll
        for (int cs = 0; cs < 4; ++cs)
#pragma unroll
          for (int i = 0; i < 4; ++i) {
            const float p = __expf(sacc[sub][cs][i] - mnew);
            sacc[sub][cs][i] = p;
            rs += p;
          }
        rs += __shfl_xor(rs, 16);
        rs += __shfl_xor(rs, 32);
        if (keep) {
          lrow[sub] += rs;
        } else {
          const float sc = __expf(mrow[sub] - mnew);
          lrow[sub] = lrow[sub] * sc + rs;
          mrow[sub] = mnew;
#pragma unroll
          for (int dt = 0; dt < 8; ++dt) oacc[sub][dt] *= sc;
        }
#pragma unroll
        for (int ch = 0; ch < 2; ++ch) {
          bf8u p;
          p.u[0] = cvt_pk2(sacc[sub][2 * ch][0],     sacc[sub][2 * ch][1]);
          p.u[1] = cvt_pk2(sacc[sub][2 * ch][2],     sacc[sub][2 * ch][3]);
          p.u[2] = cvt_pk2(sacc[sub][2 * ch + 1][0], sacc[sub][2 * ch + 1][1]);
          p.u[3] = cvt_pk2(sacc[sub][2 * ch + 1][2], sacc[sub][2 * ch + 1][3]);
          pa[sub][ch] = p.v;
        }
      };

      SM(0);                       // pa[0] ready

      // ---- issue ALL vf reads now; results not needed until after SM(1)
      //      -> SM(1)'s VALU hides the DS issue + latency ----
      bf16x8 vfr[16];
#pragma unroll
      for (int ch = 0; ch < 2; ++ch)
#pragma unroll
        for (int dt = 0; dt < 8; ++dt)
          vfr[ch * 8 + dt] = *(const bf16x8*)&Vb[vidx(dt * 16 + lo, hi * 16 + ch * 8)];

      SM(1);                       // overlaps vf loads

      // ---- PV: dense pure-register MFMA cluster ----
#pragma unroll
      for (int ch = 0; ch < 2; ++ch) {
#pragma unroll
        for (int dt = 0; dt < 8; ++dt) {
          oacc[0][dt] = __builtin_amdgcn_mfma_f32_16x16x32_bf16(vfr[ch * 8 + dt], pa[0][ch], oacc[0][dt], 0, 0, 0);
          oacc[1][dt] = __builtin_amdgcn_mfma_f32_16x16x32_bf16(vfr[ch * 8 + dt], pa[1][ch], oacc[1][dt], 0, 0, 0);
        }
      }

      __syncthreads();   // C: no VMEM in flight; drains lgkm only
    }

    // ---- epilogue: direct store ----
#pragma unroll
    for (int sub = 0; sub < 2; ++sub) {
      const float inv = 1.f / lrow[sub];
      float* orow = out + ((size_t)(b * LQ_ + qrow0 + sub * 16 + lo) * HQ_ + hq) * D_;
#pragma unroll
      for (int dt = 0; dt < 8; ++dt) {
        f32x4 o4 = oacc[sub][dt] * inv;
        *(f32x4*)(orow + dt * 16 + hi * 4) = o4;
      }
    }
  } else {
    // ================= PRODUCER: stage global -> bf16 -> LDS (R9) =====
    const int pid = tid & 255;           // 0..255
    const int cK  = pid >> 4;            // K row base (+16*i), i=0..3
    const int e   = pid & 15;            // K d-chunk (8 floats at e*8)
    const int qd  = pid >> 4;            // V row-quad 0..15
    const int dc  = pid & 15;            // V d-chunk (8 floats at dc*8)
    const int r0v = qd * 4;
    const int d0v = dc * 8;
    const int P0v = pkmap(r0v);          // rows r0v..r0v+3 -> P0v..P0v+3
    f32x4 kreg[4][2], vreg[4][2];

    auto issue_loads = [&](int t) {
      const int kbase = t * KT_;         // tile never straddles CTX
      const float *kb_, *vb_;
      if (kbase < CTX_) {
        const int pb = btab[b * BPS_ + (kbase >> 8)];
        const size_t base = ((size_t)(pb * BLKSZ_ + (kbase & 255)) * HKV_ + hkv) * D_;
        kb_ = kcache + base; vb_ = vcache + base;
      } else {
        const size_t base = ((size_t)(b * LQ_ + (kbase - CTX_)) * HKV_ + hkv) * D_;
        kb_ = kcur + base;  vb_ = vcur + base;
      }
      const size_t rs = (size_t)HKV_ * D_;
#pragma unroll
      for (int i = 0; i < 4; ++i) {
        const float* kr = kb_ + (size_t)(cK + 16 * i) * rs + e * 8;
        kreg[i][0] = *(const f32x4*)(kr);
        kreg[i][1] = *(const f32x4*)(kr + 4);
      }
#pragma unroll
      for (int m = 0; m < 4; ++m) {
        const float* vr = vb_ + (size_t)(r0v + m) * rs + d0v;
        vreg[m][0] = *(const f32x4*)(vr);
        vreg[m][1] = *(const f32x4*)(vr + 4);
      }
    };

    auto write_lds = [&](int bsel) {
      short* Kb = Kl[bsel];
      short* Vb = Vl[bsel];
#pragma unroll
      for (int i = 0; i < 4; ++i) {      // one b128 per K row-chunk
        bf8u f;
        f.u[0] = cvt_pk2(kreg[i][0][0], kreg[i][0][1]);
        f.u[1] = cvt_pk2(kreg[i][0][2], kreg[i][0][3]);
        f.u[2] = cvt_pk2(kreg[i][1][0], kreg[i][1][1]);
        f.u[3] = cvt_pk2(kreg[i][1][2], kreg[i][1][3]);
        *(bf16x8*)&Kb[kidx(cK + 16 * i, e * 8)] = f.v;
      }
#pragma unroll
      for (int j = 0; j < 8; ++j) {      // one b64 per d: 4 quad-rows packed
        u32x2 w;
        w[0] = cvt_pk2(vreg[0][j >> 2][j & 3], vreg[1][j >> 2][j & 3]);
        w[1] = cvt_pk2(vreg[2][j >> 2][j & 3], vreg[3][j >> 2][j & 3]);
        *(u32x2*)&Vb[vidx(d0v + j, P0v)] = w;
      }
    };

    issue_loads(0);
    write_lds(0);
    if (nt > 1) issue_loads(1);
    asm volatile("s_waitcnt lgkmcnt(0)" ::: "memory");
    __builtin_amdgcn_s_barrier();

    for (int t = 0; t < nt; ++t) {
      if (t + 1 < nt) write_lds((t + 1) & 1);   // auto vmcnt wait on reg use
      if (t + 2 < nt) issue_loads(t + 2);       // in flight across barrier
      asm volatile("s_waitcnt lgkmcnt(0)" ::: "memory");
      __builtin_amdgcn_s_barrier();
    }
  }
}

extern "C" void kernel_launch(void* const* d_in, const int* in_sizes, int n_in,
                              void* d_out, int out_size, void* d_ws, size_t ws_size,
                              hipStream_t stream) {
  (void)in_sizes; (void)n_in; (void)out_size; (void)d_ws; (void)ws_size;
  const float* q      = (const float*)d_in[0];
  const float* k      = (const float*)d_in[1];
  const float* v      = (const float*)d_in[2];
  const float* kcache = (const float*)d_in[3];
  const float* vcache = (const float*)d_in[4];
  const int*   btab   = (const int*)d_in[5];
  float* out = (float*)d_out;

  block_attn_kernel<<<dim3(B_ * HKV_ * (LQ_ / 64)), dim3(512), 0, stream>>>(
      q, k, v, kcache, vcache, btab, out);
}